// Round 4
// baseline (187.879 us; speedup 1.0000x reference)
//
#include <hip/hip_runtime.h>
#include <hip/hip_bf16.h>

typedef unsigned short ushortT;
typedef __bf16 bf16x8 __attribute__((ext_vector_type(8)));
typedef __bf16 bf16x4 __attribute__((ext_vector_type(4)));
typedef float f32x4 __attribute__((ext_vector_type(4)));

#define T_SEQ 2048
#define DH 64
#define NH 16
#define DM 1024
#define TD 3072
#define BATCH 2

__device__ inline ushortT f2bf(float f){
    union { float f; unsigned int u; } a; a.f = f;
    unsigned int r = a.u + 0x7fffu + ((a.u >> 16) & 1u);
    return (ushortT)(r >> 16);
}
__device__ inline float bf2f(ushortT u){
    union { float f; unsigned int u; } a; a.u = ((unsigned int)u) << 16;
    return a.f;
}

__device__ inline void gload_lds16(const void* g, void* l){
    __builtin_amdgcn_global_load_lds((const __attribute__((address_space(1))) void*)g,
                                     (__attribute__((address_space(3))) void*)l, 16, 0, 0);
}

// ---------------- cast x (fp32 -> bf16) ----------------
__global__ __launch_bounds__(256) void cast_bf16_kernel(const float* __restrict__ in,
                                                        ushortT* __restrict__ out, int n){
    int i = (blockIdx.x * 256 + threadIdx.x) * 4;
    if (i < n){
        float4 v = *(const float4*)&in[i];
        out[i+0] = f2bf(v.x); out[i+1] = f2bf(v.y);
        out[i+2] = f2bf(v.z); out[i+3] = f2bf(v.w);
    }
}

// ---------------- transpose + cast: in (K,N) fp32 -> out (N,K) bf16 ----------------
__global__ __launch_bounds__(256) void transcast_kernel(const float* __restrict__ in,
                                                        ushortT* __restrict__ out, int K, int N){
    __shared__ float tile[64][65];
    int n0 = blockIdx.x * 64, k0 = blockIdx.y * 64;
    int tid = threadIdx.x;
    int c  = tid & 63;
    int r4 = tid >> 6;
#pragma unroll
    for (int i = 0; i < 16; i++){
        int k = r4 + i * 4;
        tile[k][c] = in[(size_t)(k0 + k) * N + n0 + c];
    }
    __syncthreads();
#pragma unroll
    for (int i = 0; i < 16; i++){
        int n = r4 + i * 4;
        out[(size_t)(n0 + n) * K + k0 + c] = f2bf(tile[c][n]);
    }
}

// ---------------- bf16 MFMA GEMM: C(M,N) = A(M,K) @ BT(N,K)^T + bias ----------------
__device__ inline void store_out(ushortT* C, size_t i, float v){ C[i] = f2bf(v); }
__device__ inline void store_out(float*   C, size_t i, float v){ C[i] = v; }

template <typename OUT>
__global__ __launch_bounds__(256) void gemm_bf16_kernel(const ushortT* __restrict__ A,
                                                        const ushortT* __restrict__ BT,
                                                        const float* __restrict__ bias,
                                                        OUT* __restrict__ C,
                                                        int M, int N, int K){
    __shared__ __align__(16) ushortT As[128*32];
    __shared__ __align__(16) ushortT Bs[128*32];
    int tid = threadIdx.x;
    // XCD-aware swizzle (bijective: gridDim.x*gridDim.y % 8 == 0)
    int nwg = gridDim.x * gridDim.y;
    int id  = blockIdx.y * gridDim.x + blockIdx.x;
    int cpx = nwg >> 3;
    int nid = (id & 7) * cpx + (id >> 3);
    int bx  = nid % gridDim.x;
    int by  = nid / gridDim.x;
    int m0 = bx * 128;
    int n0 = by * 128;
    int wid = tid >> 6, lane = tid & 63;
    int l15 = lane & 15, g = lane >> 4;
    int wr = wid >> 1, wc = wid & 1;

    f32x4 acc[4][4];
#pragma unroll
    for (int i = 0; i < 4; i++)
#pragma unroll
        for (int j = 0; j < 4; j++) acc[i][j] = (f32x4){0.f,0.f,0.f,0.f};

    int srow = wid * 32 + (lane >> 2);
    int sch  = lane & 3;

    for (int k0 = 0; k0 < K; k0 += 32){
#pragma unroll
        for (int i = 0; i < 2; i++){
            int row = srow + i * 16;
            const ushortT* asrc = A  + (size_t)(m0 + row) * K + k0 + sch * 8;
            const ushortT* bsrc = BT + (size_t)(n0 + row) * K + k0 + sch * 8;
            gload_lds16(asrc, (char*)As + (wid*2 + i) * 1024);
            gload_lds16(bsrc, (char*)Bs + (wid*2 + i) * 1024);
        }
        __syncthreads();
        bf16x8 af[4], bfr[4];
#pragma unroll
        for (int mi = 0; mi < 4; mi++){
            int r = wr*64 + mi*16 + l15;
            af[mi]  = *(const bf16x8*)(As + r*32 + g*8);
        }
#pragma unroll
        for (int ni = 0; ni < 4; ni++){
            int r = wc*64 + ni*16 + l15;
            bfr[ni] = *(const bf16x8*)(Bs + r*32 + g*8);
        }
#pragma unroll
        for (int mi = 0; mi < 4; mi++)
#pragma unroll
            for (int ni = 0; ni < 4; ni++)
                acc[mi][ni] = __builtin_amdgcn_mfma_f32_16x16x32_bf16(af[mi], bfr[ni], acc[mi][ni], 0, 0, 0);
        __syncthreads();
    }

#pragma unroll
    for (int mi = 0; mi < 4; mi++){
#pragma unroll
        for (int jj = 0; jj < 4; jj++){
            int mm = m0 + wr*64 + mi*16 + 4*g + jj;
#pragma unroll
            for (int ni = 0; ni < 4; ni++){
                int nn = n0 + wc*64 + ni*16 + l15;
                float v = acc[mi][ni][jj] + bias[nn];
                store_out(C, (size_t)mm * N + nn, v);
            }
        }
    }
}

// ---------------- gate: g=sigmoid(q @ Wg[h]); VgT[b,h,e,t] = g*v  ----------------
__global__ __launch_bounds__(256) void gate_kernel(const ushortT* __restrict__ qkv,
                                                   const float* __restrict__ Wg,
                                                   ushortT* __restrict__ vgT){
    __shared__ float WgL[64][64];
    __shared__ ushortT VT[64][66];
    int tblk = blockIdx.x, bh = blockIdx.y;
    int b = bh >> 4, h = bh & 15;
    int tid = threadIdx.x, wid = tid >> 6, lane = tid & 63;

    for (int i = tid; i < 64*64; i += 256) WgL[i >> 6][i & 63] = Wg[h*4096 + i];
    __syncthreads();

    int t0 = tblk * 64;
#pragma unroll 4
    for (int i = 0; i < 16; i++){
        int tl = wid * 16 + i;
        int t = t0 + tl;
        const ushortT* qrow = qkv + ((size_t)b * T_SEQ + t) * TD + h * DH;
        const ushortT* vrow = qkv + ((size_t)b * T_SEQ + t) * TD + 2*DM + h * DH;
        float s = 0.f;
#pragma unroll
        for (int d = 0; d < 64; d++) s += bf2f(qrow[d]) * WgL[d][lane];
        float gv = 1.f / (1.f + __expf(-s));
        VT[tl][lane] = f2bf(gv * bf2f(vrow[lane]));
    }
    __syncthreads();
    for (int i = tid; i < 64*64; i += 256){
        int e = i >> 6, tl = i & 63;
        vgT[((size_t)bh * DH + e) * T_SEQ + t0 + tl] = VT[tl][e];
    }
}

// ---------------- causal flash attention with gated V ----------------
// grid: (bh=32, pair=16); block processes qblk pA=pair and pB=31-pair JOINTLY,
// streaming kv tiles 0..pB once; both q-sets consume shared staged tiles.
// Swapped QK^T: s = mfma(K, Q) -> q on lane axis (l15), keys in registers.
struct QState {
    bf16x8 qf0, qf1;
    float m_, lsum;
    f32x4 acc[4];
};

#define LOG2E 1.44269504f

__device__ __forceinline__ void proc_tile(const ushortT* __restrict__ Kb,
                                          const ushortT* __restrict__ Vb,
                                          QState& S, bool diag,
                                          int wid, int l15, int g,
                                          ushortT (*Pl)[72], float* Al){
    f32x4 s[4];
#pragma unroll
    for (int ns = 0; ns < 4; ns++){
        int kr = ns*16 + l15;
        bf16x8 kf0 = *(const bf16x8*)(Kb + kr*64 + ((g     ) ^ (kr & 7))*8);
        bf16x8 kf1 = *(const bf16x8*)(Kb + kr*64 + ((4 + g) ^ (kr & 7))*8);
        f32x4 z = (f32x4){0.f,0.f,0.f,0.f};
        z = __builtin_amdgcn_mfma_f32_16x16x32_bf16(kf0, S.qf0, z, 0, 0, 0);
        z = __builtin_amdgcn_mfma_f32_16x16x32_bf16(kf1, S.qf1, z, 0, 0, 0);
        s[ns] = z;
    }

    float tmax = -INFINITY;
    if (diag){
        int qrel = wid*16 + l15;
#pragma unroll
        for (int ns = 0; ns < 4; ns++){
            int kbase = ns*16 + 4*g;
#pragma unroll
            for (int jj = 0; jj < 4; jj++){
                if (kbase + jj > qrel) s[ns][jj] = -INFINITY;
                tmax = fmaxf(tmax, s[ns][jj]);
            }
        }
    } else {
#pragma unroll
        for (int ns = 0; ns < 4; ns++){
            float a = fmaxf(s[ns][0], s[ns][1]);
            float c = fmaxf(s[ns][2], s[ns][3]);
            tmax = fmaxf(tmax, fmaxf(a, c));
        }
    }
    tmax = fmaxf(tmax, __shfl_xor(tmax, 16, 64));
    tmax = fmaxf(tmax, __shfl_xor(tmax, 32, 64));

    float mnew = fmaxf(S.m_, tmax);
    float mc = mnew * LOG2E;
    float rs = 0.f;
#pragma unroll
    for (int ns = 0; ns < 4; ns++){
        bf16x4 pk;
#pragma unroll
        for (int jj = 0; jj < 4; jj++){
            float p = __builtin_amdgcn_exp2f(fmaf(s[ns][jj], LOG2E, -mc));
            pk[jj] = (__bf16)p;
            rs += p;
        }
        *(bf16x4*)&Pl[l15][ns*16 + 4*g] = pk;
    }
    rs += __shfl_xor(rs, 16, 64);
    rs += __shfl_xor(rs, 32, 64);

    if (!__all(mnew == S.m_)){
        float alpha = __builtin_amdgcn_exp2f(fmaf(S.m_, LOG2E, -mc));
        Al[l15] = alpha;
        f32x4 a4 = *(const f32x4*)&Al[4*g];
#pragma unroll
        for (int nt = 0; nt < 4; nt++)
#pragma unroll
            for (int jj = 0; jj < 4; jj++) S.acc[nt][jj] *= a4[jj];
        S.lsum *= alpha;
        S.m_ = mnew;
    }
    S.lsum += rs;

#pragma unroll
    for (int ks = 0; ks < 2; ks++){
        bf16x8 pa = *(const bf16x8*)&Pl[l15][ks*32 + 8*g];
#pragma unroll
        for (int nt = 0; nt < 4; nt++){
            int e = nt*16 + l15;
            bf16x8 vf = *(const bf16x8*)(Vb + e*64 + ((ks*4 + g) ^ (e & 7))*8);
            S.acc[nt] = __builtin_amdgcn_mfma_f32_16x16x32_bf16(pa, vf, S.acc[nt], 0, 0, 0);
        }
    }
}

__global__ __launch_bounds__(256) void attn_kernel(const ushortT* __restrict__ qkv,
                                                   const ushortT* __restrict__ vgT,
                                                   ushortT* __restrict__ obf){
    __shared__ __align__(16) ushortT Ks[2][64*64];
    __shared__ __align__(16) ushortT Vs[2][64*64];
    __shared__ __align__(16) ushortT Plds[2][4][16][72];
    __shared__ __align__(16) float Alds[2][4][16];
    int bh = blockIdx.x, pairid = blockIdx.y;
    int b = bh >> 4, h = bh & 15;
    int tid = threadIdx.x, wid = tid >> 6, lane = tid & 63;
    int l15 = lane & 15, g = lane >> 4;

    const ushortT* Kg = qkv + (size_t)b * T_SEQ * TD + DM + h * DH;
    const ushortT* Vg = vgT + (size_t)bh * DH * T_SEQ;

    int st_row = wid*16 + (lane >> 3);
    int st_c   = lane & 7;

#define STAGE_TILE(bufidx, kv0)                                                          \
    {                                                                                    \
        _Pragma("unroll")                                                                \
        for (int i_ = 0; i_ < 2; i_++){                                                  \
            int row_ = st_row + i_*8;                                                    \
            int sc_  = st_c ^ (row_ & 7);                                                \
            const ushortT* ksrc_ = Kg + (size_t)((kv0) + row_) * TD + sc_*8;             \
            const ushortT* vsrc_ = Vg + (size_t)row_ * T_SEQ + (kv0) + sc_*8;            \
            gload_lds16(ksrc_, (char*)Ks[bufidx] + (wid*2 + i_)*1024);                   \
            gload_lds16(vsrc_, (char*)Vs[bufidx] + (wid*2 + i_)*1024);                   \
        }                                                                                \
    }

    int pA = pairid, pB = 31 - pairid;

    QState SA, SB;
    {
        int qrow = pA*64 + wid*16 + l15;
        const ushortT* qb = qkv + ((size_t)b * T_SEQ + qrow) * TD + h * DH;
        SA.qf0 = *(const bf16x8*)(qb + 8*g);
        SA.qf1 = *(const bf16x8*)(qb + 32 + 8*g);
    }
    {
        int qrow = pB*64 + wid*16 + l15;
        const ushortT* qb = qkv + ((size_t)b * T_SEQ + qrow) * TD + h * DH;
        SB.qf0 = *(const bf16x8*)(qb + 8*g);
        SB.qf1 = *(const bf16x8*)(qb + 32 + 8*g);
    }
#pragma unroll
    for (int j = 0; j < 8; j++){
        SA.qf0[j] = (__bf16)((float)SA.qf0[j] * 0.125f);
        SA.qf1[j] = (__bf16)((float)SA.qf1[j] * 0.125f);
        SB.qf0[j] = (__bf16)((float)SB.qf0[j] * 0.125f);
        SB.qf1[j] = (__bf16)((float)SB.qf1[j] * 0.125f);
    }
    SA.m_ = -INFINITY; SA.lsum = 0.f;
    SB.m_ = -INFINITY; SB.lsum = 0.f;
#pragma unroll
    for (int nt = 0; nt < 4; nt++){
        SA.acc[nt] = (f32x4){0.f,0.f,0.f,0.f};
        SB.acc[nt] = (f32x4){0.f,0.f,0.f,0.f};
    }

    STAGE_TILE(0, 0);
    __syncthreads();

    for (int t = 0; t <= pB; t++){
        int buf = t & 1;
        if (t < pB) STAGE_TILE(buf ^ 1, (t+1)*64);
        const ushortT* Kb = Ks[buf];
        const ushortT* Vb = Vs[buf];
        if (t <= pA)
            proc_tile(Kb, Vb, SA, t == pA, wid, l15, g, Plds[0][wid], Alds[0][wid]);
        proc_tile(Kb, Vb, SB, t == pB, wid, l15, g, Plds[1][wid], Alds[1][wid]);
        __syncthreads();
    }
#undef STAGE_TILE

    // epilogues
    {
        Alds[0][wid][l15] = 1.f / SA.lsum;
        f32x4 i4 = *(const f32x4*)&Alds[0][wid][4*g];
#pragma unroll
        for (int jj = 0; jj < 4; jj++){
            int t = pA*64 + wid*16 + 4*g + jj;
#pragma unroll
            for (int nt = 0; nt < 4; nt++)
                obf[((size_t)b * T_SEQ + t) * DM + h*DH + nt*16 + l15] =
                    f2bf(SA.acc[nt][jj] * i4[jj]);
        }
    }
    {
        Alds[1][wid][l15] = 1.f / SB.lsum;
        f32x4 i4 = *(const f32x4*)&Alds[1][wid][4*g];
#pragma unroll
        for (int jj = 0; jj < 4; jj++){
            int t = pB*64 + wid*16 + 4*g + jj;
#pragma unroll
            for (int nt = 0; nt < 4; nt++)
                obf[((size_t)b * T_SEQ + t) * DM + h*DH + nt*16 + l15] =
                    f2bf(SB.acc[nt][jj] * i4[jj]);
        }
    }
}

extern "C" void kernel_launch(void* const* d_in, const int* in_sizes, int n_in,
                              void* d_out, int out_size, void* d_ws, size_t ws_size,
                              hipStream_t stream){
    const float* x    = (const float*)d_in[0];
    const float* Wqkv = (const float*)d_in[1];
    const float* bqkv = (const float*)d_in[2];
    const float* Wg   = (const float*)d_in[3];
    const float* Wout = (const float*)d_in[4];
    const float* bout = (const float*)d_in[5];

    char* ws = (char*)d_ws;
    ushortT* xbf   = (ushortT*)(ws);                 //  8 MB : (4096,1024) bf16
    ushortT* wqkvT = (ushortT*)(ws + 8388608);       //  6 MB : (3072,1024) bf16
    ushortT* woutT = (ushortT*)(ws + 14680064);      //  2 MB : (1024,1024) bf16
    ushortT* qkvb  = (ushortT*)(ws + 16777216);      // 24 MB : (4096,3072) bf16
    ushortT* vgT   = (ushortT*)(ws + 41943040);      //  8 MB : (32,64,2048) bf16
    ushortT* obf   = (ushortT*)(ws + 50331648);      //  8 MB : (4096,1024) bf16

    cast_bf16_kernel<<<4096, 256, 0, stream>>>(x, xbf, 4194304);
    transcast_kernel<<<dim3(48,16), 256, 0, stream>>>(Wqkv, wqkvT, 1024, 3072);
    transcast_kernel<<<dim3(16,16), 256, 0, stream>>>(Wout, woutT, 1024, 1024);
    gemm_bf16_kernel<ushortT><<<dim3(32,24), 256, 0, stream>>>(xbf, wqkvT, bqkv, qkvb, 4096, 3072, 1024);
    gate_kernel<<<dim3(32,32), 256, 0, stream>>>(qkvb, Wg, vgT);
    attn_kernel<<<dim3(32,16), 256, 0, stream>>>(qkvb, vgT, obf);
    gemm_bf16_kernel<float><<<dim3(32,8), 256, 0, stream>>>(obf, woutT, bout, (float*)d_out, 4096, 1024, 1024);
}

// Round 5
// 131.229 us; speedup vs baseline: 1.4317x; 1.4317x over previous
//
#include <hip/hip_runtime.h>
#include <hip/hip_bf16.h>

typedef unsigned short ushortT;
typedef __bf16 bf16x8 __attribute__((ext_vector_type(8)));
typedef __bf16 bf16x4 __attribute__((ext_vector_type(4)));
typedef float f32x4 __attribute__((ext_vector_type(4)));

#define T_SEQ 2048
#define DH 64
#define NH 16
#define DM 1024
#define TD 3072
#define BATCH 2
#define LOG2E 1.44269504f

__device__ inline ushortT f2bf(float f){
    union { float f; unsigned int u; } a; a.f = f;
    unsigned int r = a.u + 0x7fffu + ((a.u >> 16) & 1u);
    return (ushortT)(r >> 16);
}
__device__ inline float bf2f(ushortT u){
    union { float f; unsigned int u; } a; a.u = ((unsigned int)u) << 16;
    return a.f;
}

__device__ inline void gload_lds16(const void* g, void* l){
    __builtin_amdgcn_global_load_lds((const __attribute__((address_space(1))) void*)g,
                                     (__attribute__((address_space(3))) void*)l, 16, 0, 0);
}

// ---------------- cast x (fp32 -> bf16) ----------------
__global__ __launch_bounds__(256) void cast_bf16_kernel(const float* __restrict__ in,
                                                        ushortT* __restrict__ out, int n){
    int i = (blockIdx.x * 256 + threadIdx.x) * 4;
    if (i < n){
        float4 v = *(const float4*)&in[i];
        out[i+0] = f2bf(v.x); out[i+1] = f2bf(v.y);
        out[i+2] = f2bf(v.z); out[i+3] = f2bf(v.w);
    }
}

// ---------------- transpose + cast: in (K,N) fp32 -> out (N,K) bf16 ----------------
__global__ __launch_bounds__(256) void transcast_kernel(const float* __restrict__ in,
                                                        ushortT* __restrict__ out, int K, int N){
    __shared__ float tile[64][65];
    int n0 = blockIdx.x * 64, k0 = blockIdx.y * 64;
    int tid = threadIdx.x;
    int c  = tid & 63;
    int r4 = tid >> 6;
#pragma unroll
    for (int i = 0; i < 16; i++){
        int k = r4 + i * 4;
        tile[k][c] = in[(size_t)(k0 + k) * N + n0 + c];
    }
    __syncthreads();
#pragma unroll
    for (int i = 0; i < 16; i++){
        int n = r4 + i * 4;
        out[(size_t)(n0 + n) * K + k0 + c] = f2bf(tile[c][n]);
    }
}

// ---------------- Wg transpose: in [16][d=64][e=64] f32 -> out [16][e][d] bf16 ----------------
__global__ __launch_bounds__(256) void wg_transcast_kernel(const float* __restrict__ in,
                                                           ushortT* __restrict__ out){
    __shared__ float tile[64][65];
    int h = blockIdx.x;
    int tid = threadIdx.x;
    int c = tid & 63, r4 = tid >> 6;
#pragma unroll
    for (int i = 0; i < 16; i++){
        int d = r4 + i*4;
        tile[d][c] = in[h*4096 + d*64 + c];
    }
    __syncthreads();
#pragma unroll
    for (int i = 0; i < 16; i++){
        int e = r4 + i*4;
        out[h*4096 + e*64 + c] = f2bf(tile[c][e]);   // out[h][e][d=c]
    }
}

// ---------------- bf16 MFMA GEMM (2-phase double-buffered): C = A @ BT^T + bias ----------------
__device__ inline void store_out(ushortT* C, size_t i, float v){ C[i] = f2bf(v); }
__device__ inline void store_out(float*   C, size_t i, float v){ C[i] = v; }

template <typename OUT>
__global__ __launch_bounds__(256) void gemm_bf16_kernel(const ushortT* __restrict__ A,
                                                        const ushortT* __restrict__ BT,
                                                        const float* __restrict__ bias,
                                                        OUT* __restrict__ C,
                                                        int M, int N, int K){
    __shared__ __align__(16) ushortT As[2][128*32];
    __shared__ __align__(16) ushortT Bs[2][128*32];
    int tid = threadIdx.x;
    int m0 = blockIdx.x * 128;
    int n0 = blockIdx.y * 128;
    int wid = tid >> 6, lane = tid & 63;
    int l15 = lane & 15, g = lane >> 4;
    int wr = wid >> 1, wc = wid & 1;

    f32x4 acc[4][4];
#pragma unroll
    for (int i = 0; i < 4; i++)
#pragma unroll
        for (int j = 0; j < 4; j++) acc[i][j] = (f32x4){0.f,0.f,0.f,0.f};

    int srow = wid * 32 + (lane >> 2);
    int sch  = lane & 3;

#define GSTAGE(buf, k0)                                                                  \
    {                                                                                    \
        _Pragma("unroll")                                                                \
        for (int i_ = 0; i_ < 2; i_++){                                                  \
            int row_ = srow + i_ * 16;                                                   \
            const ushortT* asrc_ = A  + (size_t)(m0 + row_) * K + (k0) + sch * 8;        \
            const ushortT* bsrc_ = BT + (size_t)(n0 + row_) * K + (k0) + sch * 8;        \
            gload_lds16(asrc_, (char*)As[buf] + (wid*2 + i_) * 1024);                    \
            gload_lds16(bsrc_, (char*)Bs[buf] + (wid*2 + i_) * 1024);                    \
        }                                                                                \
    }

    GSTAGE(0, 0);
    __syncthreads();

    int nk = K >> 5;
    for (int kt = 0; kt < nk; kt++){
        int buf = kt & 1;
        if (kt + 1 < nk) GSTAGE(buf ^ 1, (kt + 1) * 32);

        bf16x8 af[4], bfr[4];
#pragma unroll
        for (int mi = 0; mi < 4; mi++){
            int r = wr*64 + mi*16 + l15;
            af[mi]  = *(const bf16x8*)(As[buf] + r*32 + g*8);
        }
#pragma unroll
        for (int ni = 0; ni < 4; ni++){
            int r = wc*64 + ni*16 + l15;
            bfr[ni] = *(const bf16x8*)(Bs[buf] + r*32 + g*8);
        }
#pragma unroll
        for (int mi = 0; mi < 4; mi++)
#pragma unroll
            for (int ni = 0; ni < 4; ni++)
                acc[mi][ni] = __builtin_amdgcn_mfma_f32_16x16x32_bf16(af[mi], bfr[ni], acc[mi][ni], 0, 0, 0);
        __syncthreads();
    }
#undef GSTAGE

#pragma unroll
    for (int mi = 0; mi < 4; mi++){
#pragma unroll
        for (int jj = 0; jj < 4; jj++){
            int mm = m0 + wr*64 + mi*16 + 4*g + jj;
#pragma unroll
            for (int ni = 0; ni < 4; ni++){
                int nn = n0 + wc*64 + ni*16 + l15;
                float v = acc[mi][ni][jj] + bias[nn];
                store_out(C, (size_t)mm * N + nn, v);
            }
        }
    }
}

// ---------------- gate (MFMA): g=sigmoid(Q @ Wg[h]); VgT[b,h,e,t] = g*v ----------------
__global__ __launch_bounds__(256) void gate_kernel(const ushortT* __restrict__ qkv,
                                                   const ushortT* __restrict__ WgT,
                                                   ushortT* __restrict__ vgT){
    __shared__ __align__(16) ushortT VT[64][72];
    int tblk = blockIdx.x, bh = blockIdx.y;
    int b = bh >> 4, h = bh & 15;
    int tid = threadIdx.x, wid = tid >> 6, lane = tid & 63;
    int l15 = lane & 15, g = lane >> 4;
    int t0 = tblk * 64;
    int tl = wid*16 + l15;

    const ushortT* qrow = qkv + ((size_t)b*T_SEQ + t0 + tl)*TD + h*DH;
    bf16x8 qf0 = *(const bf16x8*)(qrow + 8*g);
    bf16x8 qf1 = *(const bf16x8*)(qrow + 32 + 8*g);

    const ushortT* wbase = WgT + h*4096;
    const ushortT* vrow = qkv + ((size_t)b*T_SEQ + t0 + tl)*TD + 2*DM + h*DH;

#pragma unroll
    for (int ns = 0; ns < 4; ns++){
        int e = ns*16 + l15;
        bf16x8 wf0 = *(const bf16x8*)(wbase + e*64 + 8*g);
        bf16x8 wf1 = *(const bf16x8*)(wbase + e*64 + 32 + 8*g);
        f32x4 z = (f32x4){0.f,0.f,0.f,0.f};
        z = __builtin_amdgcn_mfma_f32_16x16x32_bf16(wf0, qf0, z, 0, 0, 0);
        z = __builtin_amdgcn_mfma_f32_16x16x32_bf16(wf1, qf1, z, 0, 0, 0);
        // z[jj] = G[e=ns*16+4g+jj][t=tl]
        union { ushortT u[4]; uint2 v; } v4;
        v4.v = *(const uint2*)(vrow + ns*16 + 4*g);
#pragma unroll
        for (int jj = 0; jj < 4; jj++){
            float ex = __builtin_amdgcn_exp2f(-z[jj] * LOG2E);
            float gv = __builtin_amdgcn_rcpf(1.f + ex);
            VT[ns*16 + 4*g + jj][tl] = f2bf(gv * bf2f(v4.u[jj]));
        }
    }
    __syncthreads();
    // write VgT[bh][e][t0..t0+63] vectorized (16B per lane)
    for (int i = tid; i < 64*8; i += 256){
        int e = i >> 3, c8 = (i & 7) * 8;
        *(uint4*)&vgT[((size_t)bh * DH + e) * T_SEQ + t0 + c8] = *(const uint4*)&VT[e][c8];
    }
}

// ---------------- causal flash attention with gated V ----------------
struct QState {
    bf16x8 qf0, qf1;
    float m_, lsum;
    f32x4 acc[4];
};

__device__ __forceinline__ void proc_tile(const ushortT* __restrict__ Kb,
                                          const ushortT* __restrict__ Vb,
                                          QState& S, bool diag,
                                          int wid, int l15, int g,
                                          ushortT (*Pl)[72], float* Al){
    f32x4 s[4];
    __builtin_amdgcn_s_setprio(1);
#pragma unroll
    for (int ns = 0; ns < 4; ns++){
        int kr = ns*16 + l15;
        bf16x8 kf0 = *(const bf16x8*)(Kb + kr*64 + ((g     ) ^ (kr & 7))*8);
        bf16x8 kf1 = *(const bf16x8*)(Kb + kr*64 + ((4 + g) ^ (kr & 7))*8);
        f32x4 z = (f32x4){0.f,0.f,0.f,0.f};
        z = __builtin_amdgcn_mfma_f32_16x16x32_bf16(kf0, S.qf0, z, 0, 0, 0);
        z = __builtin_amdgcn_mfma_f32_16x16x32_bf16(kf1, S.qf1, z, 0, 0, 0);
        s[ns] = z;
    }
    __builtin_amdgcn_s_setprio(0);

    float tmax = -INFINITY;
    if (diag){
        int qrel = wid*16 + l15;
#pragma unroll
        for (int ns = 0; ns < 4; ns++){
            int kbase = ns*16 + 4*g;
#pragma unroll
            for (int jj = 0; jj < 4; jj++){
                if (kbase + jj > qrel) s[ns][jj] = -INFINITY;
                tmax = fmaxf(tmax, s[ns][jj]);
            }
        }
    } else {
#pragma unroll
        for (int ns = 0; ns < 4; ns++){
            float a = fmaxf(s[ns][0], s[ns][1]);
            float c = fmaxf(s[ns][2], s[ns][3]);
            tmax = fmaxf(tmax, fmaxf(a, c));
        }
    }
    tmax = fmaxf(tmax, __shfl_xor(tmax, 16, 64));
    tmax = fmaxf(tmax, __shfl_xor(tmax, 32, 64));

    float mnew = fmaxf(S.m_, tmax);
    float mc = mnew * LOG2E;
    float rs = 0.f;
#pragma unroll
    for (int ns = 0; ns < 4; ns++){
        bf16x4 pk;
#pragma unroll
        for (int jj = 0; jj < 4; jj++){
            float p = __builtin_amdgcn_exp2f(fmaf(s[ns][jj], LOG2E, -mc));
            pk[jj] = (__bf16)p;
            rs += p;
        }
        *(bf16x4*)&Pl[l15][ns*16 + 4*g] = pk;
    }
    rs += __shfl_xor(rs, 16, 64);
    rs += __shfl_xor(rs, 32, 64);

    if (!__all(mnew == S.m_)){
        float alpha = __builtin_amdgcn_exp2f(fmaf(S.m_, LOG2E, -mc));
        Al[l15] = alpha;
        f32x4 a4 = *(const f32x4*)&Al[4*g];
#pragma unroll
        for (int nt = 0; nt < 4; nt++)
#pragma unroll
            for (int jj = 0; jj < 4; jj++) S.acc[nt][jj] *= a4[jj];
        S.lsum *= alpha;
        S.m_ = mnew;
    }
    S.lsum += rs;

    __builtin_amdgcn_s_setprio(1);
#pragma unroll
    for (int ks = 0; ks < 2; ks++){
        bf16x8 pa = *(const bf16x8*)&Pl[l15][ks*32 + 8*g];
#pragma unroll
        for (int nt = 0; nt < 4; nt++){
            int e = nt*16 + l15;
            bf16x8 vf = *(const bf16x8*)(Vb + e*64 + ((ks*4 + g) ^ (e & 7))*8);
            S.acc[nt] = __builtin_amdgcn_mfma_f32_16x16x32_bf16(pa, vf, S.acc[nt], 0, 0, 0);
        }
    }
    __builtin_amdgcn_s_setprio(0);
}

__global__ __launch_bounds__(256) void attn_kernel(const ushortT* __restrict__ qkv,
                                                   const ushortT* __restrict__ vgT,
                                                   ushortT* __restrict__ obf){
    __shared__ __align__(16) ushortT Ks[2][64*64];
    __shared__ __align__(16) ushortT Vs[2][64*64];
    __shared__ __align__(16) ushortT Plds[2][4][16][72];
    __shared__ __align__(16) float Alds[2][4][16];
    int bh = blockIdx.x, pairid = blockIdx.y;
    int b = bh >> 4, h = bh & 15;
    int tid = threadIdx.x, wid = tid >> 6, lane = tid & 63;
    int l15 = lane & 15, g = lane >> 4;

    const ushortT* Kg = qkv + (size_t)b * T_SEQ * TD + DM + h * DH;
    const ushortT* Vg = vgT + (size_t)bh * DH * T_SEQ;

    int st_row = wid*16 + (lane >> 3);
    int st_c   = lane & 7;

#define STAGE_TILE(bufidx, kv0)                                                          \
    {                                                                                    \
        _Pragma("unroll")                                                                \
        for (int i_ = 0; i_ < 2; i_++){                                                  \
            int row_ = st_row + i_*8;                                                    \
            int sc_  = st_c ^ (row_ & 7);                                                \
            const ushortT* ksrc_ = Kg + (size_t)((kv0) + row_) * TD + sc_*8;             \
            const ushortT* vsrc_ = Vg + (size_t)row_ * T_SEQ + (kv0) + sc_*8;            \
            gload_lds16(ksrc_, (char*)Ks[bufidx] + (wid*2 + i_)*1024);                   \
            gload_lds16(vsrc_, (char*)Vs[bufidx] + (wid*2 + i_)*1024);                   \
        }                                                                                \
    }

    int pA = pairid, pB = 31 - pairid;

    QState SA, SB;
    {
        int qrow = pA*64 + wid*16 + l15;
        const ushortT* qb = qkv + ((size_t)b * T_SEQ + qrow) * TD + h * DH;
        SA.qf0 = *(const bf16x8*)(qb + 8*g);
        SA.qf1 = *(const bf16x8*)(qb + 32 + 8*g);
    }
    {
        int qrow = pB*64 + wid*16 + l15;
        const ushortT* qb = qkv + ((size_t)b * T_SEQ + qrow) * TD + h * DH;
        SB.qf0 = *(const bf16x8*)(qb + 8*g);
        SB.qf1 = *(const bf16x8*)(qb + 32 + 8*g);
    }
#pragma unroll
    for (int j = 0; j < 8; j++){
        SA.qf0[j] = (__bf16)((float)SA.qf0[j] * 0.125f);
        SA.qf1[j] = (__bf16)((float)SA.qf1[j] * 0.125f);
        SB.qf0[j] = (__bf16)((float)SB.qf0[j] * 0.125f);
        SB.qf1[j] = (__bf16)((float)SB.qf1[j] * 0.125f);
    }
    SA.m_ = -INFINITY; SA.lsum = 0.f;
    SB.m_ = -INFINITY; SB.lsum = 0.f;
#pragma unroll
    for (int nt = 0; nt < 4; nt++){
        SA.acc[nt] = (f32x4){0.f,0.f,0.f,0.f};
        SB.acc[nt] = (f32x4){0.f,0.f,0.f,0.f};
    }

    STAGE_TILE(0, 0);
    __syncthreads();

    for (int t = 0; t <= pB; t++){
        int buf = t & 1;
        if (t < pB) STAGE_TILE(buf ^ 1, (t+1)*64);
        const ushortT* Kb = Ks[buf];
        const ushortT* Vb = Vs[buf];
        if (t <= pA)
            proc_tile(Kb, Vb, SA, t == pA, wid, l15, g, Plds[0][wid], Alds[0][wid]);
        proc_tile(Kb, Vb, SB, t == pB, wid, l15, g, Plds[1][wid], Alds[1][wid]);
        __syncthreads();
    }
#undef STAGE_TILE

    {
        Alds[0][wid][l15] = 1.f / SA.lsum;
        f32x4 i4 = *(const f32x4*)&Alds[0][wid][4*g];
#pragma unroll
        for (int jj = 0; jj < 4; jj++){
            int t = pA*64 + wid*16 + 4*g + jj;
#pragma unroll
            for (int nt = 0; nt < 4; nt++)
                obf[((size_t)b * T_SEQ + t) * DM + h*DH + nt*16 + l15] =
                    f2bf(SA.acc[nt][jj] * i4[jj]);
        }
    }
    {
        Alds[1][wid][l15] = 1.f / SB.lsum;
        f32x4 i4 = *(const f32x4*)&Alds[1][wid][4*g];
#pragma unroll
        for (int jj = 0; jj < 4; jj++){
            int t = pB*64 + wid*16 + 4*g + jj;
#pragma unroll
            for (int nt = 0; nt < 4; nt++)
                obf[((size_t)b * T_SEQ + t) * DM + h*DH + nt*16 + l15] =
                    f2bf(SB.acc[nt][jj] * i4[jj]);
        }
    }
}

extern "C" void kernel_launch(void* const* d_in, const int* in_sizes, int n_in,
                              void* d_out, int out_size, void* d_ws, size_t ws_size,
                              hipStream_t stream){
    const float* x    = (const float*)d_in[0];
    const float* Wqkv = (const float*)d_in[1];
    const float* bqkv = (const float*)d_in[2];
    const float* Wg   = (const float*)d_in[3];
    const float* Wout = (const float*)d_in[4];
    const float* bout = (const float*)d_in[5];

    char* ws = (char*)d_ws;
    ushortT* xbf   = (ushortT*)(ws);                 //  8 MB : (4096,1024) bf16
    ushortT* wqkvT = (ushortT*)(ws + 8388608);       //  6 MB : (3072,1024) bf16
    ushortT* woutT = (ushortT*)(ws + 14680064);      //  2 MB : (1024,1024) bf16
    ushortT* qkvb  = (ushortT*)(ws + 16777216);      // 24 MB : (4096,3072) bf16
    ushortT* vgT   = (ushortT*)(ws + 41943040);      //  8 MB : (32,64,2048) bf16
    ushortT* obf   = (ushortT*)(ws + 50331648);      //  8 MB : (4096,1024) bf16
    ushortT* wgT   = (ushortT*)(ws + 58720256);      // 128KB : (16,64,64) bf16

    cast_bf16_kernel<<<4096, 256, 0, stream>>>(x, xbf, 4194304);
    transcast_kernel<<<dim3(48,16), 256, 0, stream>>>(Wqkv, wqkvT, 1024, 3072);
    transcast_kernel<<<dim3(16,16), 256, 0, stream>>>(Wout, woutT, 1024, 1024);
    wg_transcast_kernel<<<16, 256, 0, stream>>>(Wg, wgT);
    gemm_bf16_kernel<ushortT><<<dim3(32,24), 256, 0, stream>>>(xbf, wqkvT, bqkv, qkvb, 4096, 3072, 1024);
    gate_kernel<<<dim3(32,32), 256, 0, stream>>>(qkvb, wgT, vgT);
    attn_kernel<<<dim3(32,16), 256, 0, stream>>>(qkvb, vgT, obf);
    gemm_bf16_kernel<float><<<dim3(32,8), 256, 0, stream>>>(obf, woutT, bout, (float*)d_out, 4096, 1024, 1024);
}

// Round 6
// 126.354 us; speedup vs baseline: 1.4869x; 1.0386x over previous
//
#include <hip/hip_runtime.h>
#include <hip/hip_bf16.h>

typedef unsigned short ushortT;
typedef __bf16 bf16x8 __attribute__((ext_vector_type(8)));
typedef __bf16 bf16x4 __attribute__((ext_vector_type(4)));
typedef float f32x4 __attribute__((ext_vector_type(4)));

#define T_SEQ 2048
#define DH 64
#define NH 16
#define DM 1024
#define TD 3072
#define BATCH 2
#define LOG2E 1.44269504f

__device__ inline ushortT f2bf(float f){
    union { float f; unsigned int u; } a; a.f = f;
    unsigned int r = a.u + 0x7fffu + ((a.u >> 16) & 1u);
    return (ushortT)(r >> 16);
}
__device__ inline float bf2f(ushortT u){
    union { float f; unsigned int u; } a; a.u = ((unsigned int)u) << 16;
    return a.f;
}

__device__ inline void gload_lds16(const void* g, void* l){
    __builtin_amdgcn_global_load_lds((const __attribute__((address_space(1))) void*)g,
                                     (__attribute__((address_space(3))) void*)l, 16, 0, 0);
}

// ---------------- cast x (fp32 -> bf16) ----------------
__global__ __launch_bounds__(256) void cast_bf16_kernel(const float* __restrict__ in,
                                                        ushortT* __restrict__ out, int n){
    int i = (blockIdx.x * 256 + threadIdx.x) * 4;
    if (i < n){
        float4 v = *(const float4*)&in[i];
        out[i+0] = f2bf(v.x); out[i+1] = f2bf(v.y);
        out[i+2] = f2bf(v.z); out[i+3] = f2bf(v.w);
    }
}

// ---------------- transpose + cast: in (K,N) fp32 -> out (N,K) bf16 ----------------
__global__ __launch_bounds__(256) void transcast_kernel(const float* __restrict__ in,
                                                        ushortT* __restrict__ out, int K, int N){
    __shared__ float tile[64][65];
    int n0 = blockIdx.x * 64, k0 = blockIdx.y * 64;
    int tid = threadIdx.x;
    int c  = tid & 63;
    int r4 = tid >> 6;
#pragma unroll
    for (int i = 0; i < 16; i++){
        int k = r4 + i * 4;
        tile[k][c] = in[(size_t)(k0 + k) * N + n0 + c];
    }
    __syncthreads();
#pragma unroll
    for (int i = 0; i < 16; i++){
        int n = r4 + i * 4;
        out[(size_t)(n0 + n) * K + k0 + c] = f2bf(tile[c][n]);
    }
}

// ---------------- Wg transpose: in [16][d=64][e=64] f32 -> out [16][e][d] bf16 ----------------
__global__ __launch_bounds__(256) void wg_transcast_kernel(const float* __restrict__ in,
                                                           ushortT* __restrict__ out){
    __shared__ float tile[64][65];
    int h = blockIdx.x;
    int tid = threadIdx.x;
    int c = tid & 63, r4 = tid >> 6;
#pragma unroll
    for (int i = 0; i < 16; i++){
        int d = r4 + i*4;
        tile[d][c] = in[h*4096 + d*64 + c];
    }
    __syncthreads();
#pragma unroll
    for (int i = 0; i < 16; i++){
        int e = r4 + i*4;
        out[h*4096 + e*64 + c] = f2bf(tile[c][e]);   // out[h][e][d=c]
    }
}

// ---------------- bf16 MFMA GEMM (2-phase double-buffered): C = A @ BT^T + bias ----------------
__device__ inline void store_out(ushortT* C, size_t i, float v){ C[i] = f2bf(v); }
__device__ inline void store_out(float*   C, size_t i, float v){ C[i] = v; }

template <typename OUT>
__global__ __launch_bounds__(256) void gemm_bf16_kernel(const ushortT* __restrict__ A,
                                                        const ushortT* __restrict__ BT,
                                                        const float* __restrict__ bias,
                                                        OUT* __restrict__ C,
                                                        int M, int N, int K){
    __shared__ __align__(16) ushortT As[2][128*32];
    __shared__ __align__(16) ushortT Bs[2][128*32];
    int tid = threadIdx.x;
    int m0 = blockIdx.x * 128;
    int n0 = blockIdx.y * 128;
    int wid = tid >> 6, lane = tid & 63;
    int l15 = lane & 15, g = lane >> 4;
    int wr = wid >> 1, wc = wid & 1;

    f32x4 acc[4][4];
#pragma unroll
    for (int i = 0; i < 4; i++)
#pragma unroll
        for (int j = 0; j < 4; j++) acc[i][j] = (f32x4){0.f,0.f,0.f,0.f};

    int srow = wid * 32 + (lane >> 2);
    int sch  = lane & 3;

#define GSTAGE(buf, k0)                                                                  \
    {                                                                                    \
        _Pragma("unroll")                                                                \
        for (int i_ = 0; i_ < 2; i_++){                                                  \
            int row_ = srow + i_ * 16;                                                   \
            const ushortT* asrc_ = A  + (size_t)(m0 + row_) * K + (k0) + sch * 8;        \
            const ushortT* bsrc_ = BT + (size_t)(n0 + row_) * K + (k0) + sch * 8;        \
            gload_lds16(asrc_, (char*)As[buf] + (wid*2 + i_) * 1024);                    \
            gload_lds16(bsrc_, (char*)Bs[buf] + (wid*2 + i_) * 1024);                    \
        }                                                                                \
    }

    GSTAGE(0, 0);
    __syncthreads();

    int nk = K >> 5;
    for (int kt = 0; kt < nk; kt++){
        int buf = kt & 1;
        if (kt + 1 < nk) GSTAGE(buf ^ 1, (kt + 1) * 32);

        bf16x8 af[4], bfr[4];
#pragma unroll
        for (int mi = 0; mi < 4; mi++){
            int r = wr*64 + mi*16 + l15;
            af[mi]  = *(const bf16x8*)(As[buf] + r*32 + g*8);
        }
#pragma unroll
        for (int ni = 0; ni < 4; ni++){
            int r = wc*64 + ni*16 + l15;
            bfr[ni] = *(const bf16x8*)(Bs[buf] + r*32 + g*8);
        }
#pragma unroll
        for (int mi = 0; mi < 4; mi++)
#pragma unroll
            for (int ni = 0; ni < 4; ni++)
                acc[mi][ni] = __builtin_amdgcn_mfma_f32_16x16x32_bf16(af[mi], bfr[ni], acc[mi][ni], 0, 0, 0);
        __syncthreads();
    }
#undef GSTAGE

#pragma unroll
    for (int mi = 0; mi < 4; mi++){
#pragma unroll
        for (int jj = 0; jj < 4; jj++){
            int mm = m0 + wr*64 + mi*16 + 4*g + jj;
#pragma unroll
            for (int ni = 0; ni < 4; ni++){
                int nn = n0 + wc*64 + ni*16 + l15;
                float v = acc[mi][ni][jj] + bias[nn];
                store_out(C, (size_t)mm * N + nn, v);
            }
        }
    }
}

// ---------------- gate (MFMA): g=sigmoid(Q @ Wg[h]); VgT[b,h,e,t] = g*v ----------------
__global__ __launch_bounds__(256) void gate_kernel(const ushortT* __restrict__ qkv,
                                                   const ushortT* __restrict__ WgT,
                                                   ushortT* __restrict__ vgT){
    __shared__ __align__(16) ushortT VT[64][72];
    int tblk = blockIdx.x, bh = blockIdx.y;
    int b = bh >> 4, h = bh & 15;
    int tid = threadIdx.x, wid = tid >> 6, lane = tid & 63;
    int l15 = lane & 15, g = lane >> 4;
    int t0 = tblk * 64;
    int tl = wid*16 + l15;

    const ushortT* qrow = qkv + ((size_t)b*T_SEQ + t0 + tl)*TD + h*DH;
    bf16x8 qf0 = *(const bf16x8*)(qrow + 8*g);
    bf16x8 qf1 = *(const bf16x8*)(qrow + 32 + 8*g);

    const ushortT* wbase = WgT + h*4096;
    const ushortT* vrow = qkv + ((size_t)b*T_SEQ + t0 + tl)*TD + 2*DM + h*DH;

#pragma unroll
    for (int ns = 0; ns < 4; ns++){
        int e = ns*16 + l15;
        bf16x8 wf0 = *(const bf16x8*)(wbase + e*64 + 8*g);
        bf16x8 wf1 = *(const bf16x8*)(wbase + e*64 + 32 + 8*g);
        f32x4 z = (f32x4){0.f,0.f,0.f,0.f};
        z = __builtin_amdgcn_mfma_f32_16x16x32_bf16(wf0, qf0, z, 0, 0, 0);
        z = __builtin_amdgcn_mfma_f32_16x16x32_bf16(wf1, qf1, z, 0, 0, 0);
        union { ushortT u[4]; uint2 v; } v4;
        v4.v = *(const uint2*)(vrow + ns*16 + 4*g);
#pragma unroll
        for (int jj = 0; jj < 4; jj++){
            float ex = __builtin_amdgcn_exp2f(-z[jj] * LOG2E);
            float gv = __builtin_amdgcn_rcpf(1.f + ex);
            VT[ns*16 + 4*g + jj][tl] = f2bf(gv * bf2f(v4.u[jj]));
        }
    }
    __syncthreads();
    for (int i = tid; i < 64*8; i += 256){
        int e = i >> 3, c8 = (i & 7) * 8;
        *(uint4*)&vgT[((size_t)bh * DH + e) * T_SEQ + t0 + c8] = *(const uint4*)&VT[e][c8];
    }
}

// ---------------- causal flash attention with gated V ----------------
// grid (bh=32, pair=16), block = 512 threads (8 waves).
// Waves 0-3 own qblk pA=pair (16 q-rows each); waves 4-7 own qblk pB=31-pair.
// All waves share staged K/V tiles; kv tiles streamed 0..pB once.
struct QState {
    bf16x8 qf0, qf1;
    float m_, lsum;
    f32x4 acc[4];
};

__device__ __forceinline__ void proc_tile(const ushortT* __restrict__ Kb,
                                          const ushortT* __restrict__ Vb,
                                          QState& S, bool diag,
                                          int wg, int l15, int g,
                                          ushortT (*Pl)[72], float* Al){
    f32x4 s[4];
    __builtin_amdgcn_s_setprio(1);
#pragma unroll
    for (int ns = 0; ns < 4; ns++){
        int kr = ns*16 + l15;
        bf16x8 kf0 = *(const bf16x8*)(Kb + kr*64 + ((g     ) ^ (kr & 7))*8);
        bf16x8 kf1 = *(const bf16x8*)(Kb + kr*64 + ((4 + g) ^ (kr & 7))*8);
        f32x4 z = (f32x4){0.f,0.f,0.f,0.f};
        z = __builtin_amdgcn_mfma_f32_16x16x32_bf16(kf0, S.qf0, z, 0, 0, 0);
        z = __builtin_amdgcn_mfma_f32_16x16x32_bf16(kf1, S.qf1, z, 0, 0, 0);
        s[ns] = z;
    }
    __builtin_amdgcn_s_setprio(0);

    float tmax = -INFINITY;
    if (diag){
        int qrel = wg*16 + l15;
#pragma unroll
        for (int ns = 0; ns < 4; ns++){
            int kbase = ns*16 + 4*g;
#pragma unroll
            for (int jj = 0; jj < 4; jj++){
                if (kbase + jj > qrel) s[ns][jj] = -INFINITY;
                tmax = fmaxf(tmax, s[ns][jj]);
            }
        }
    } else {
#pragma unroll
        for (int ns = 0; ns < 4; ns++){
            float a = fmaxf(s[ns][0], s[ns][1]);
            float c = fmaxf(s[ns][2], s[ns][3]);
            tmax = fmaxf(tmax, fmaxf(a, c));
        }
    }
    tmax = fmaxf(tmax, __shfl_xor(tmax, 16, 64));
    tmax = fmaxf(tmax, __shfl_xor(tmax, 32, 64));

    float mnew = fmaxf(S.m_, tmax);
    float mc = mnew * LOG2E;
    float rs = 0.f;
#pragma unroll
    for (int ns = 0; ns < 4; ns++){
        bf16x4 pk;
#pragma unroll
        for (int jj = 0; jj < 4; jj++){
            float p = __builtin_amdgcn_exp2f(fmaf(s[ns][jj], LOG2E, -mc));
            pk[jj] = (__bf16)p;
            rs += p;
        }
        *(bf16x4*)&Pl[l15][ns*16 + 4*g] = pk;
    }
    rs += __shfl_xor(rs, 16, 64);
    rs += __shfl_xor(rs, 32, 64);

    if (!__all(mnew == S.m_)){
        float alpha = __builtin_amdgcn_exp2f(fmaf(S.m_, LOG2E, -mc));
        Al[l15] = alpha;
        f32x4 a4 = *(const f32x4*)&Al[4*g];
#pragma unroll
        for (int nt = 0; nt < 4; nt++)
#pragma unroll
            for (int jj = 0; jj < 4; jj++) S.acc[nt][jj] *= a4[jj];
        S.lsum *= alpha;
        S.m_ = mnew;
    }
    S.lsum += rs;

    __builtin_amdgcn_s_setprio(1);
#pragma unroll
    for (int ks = 0; ks < 2; ks++){
        bf16x8 pa = *(const bf16x8*)&Pl[l15][ks*32 + 8*g];
#pragma unroll
        for (int nt = 0; nt < 4; nt++){
            int e = nt*16 + l15;
            bf16x8 vf = *(const bf16x8*)(Vb + e*64 + ((ks*4 + g) ^ (e & 7))*8);
            S.acc[nt] = __builtin_amdgcn_mfma_f32_16x16x32_bf16(pa, vf, S.acc[nt], 0, 0, 0);
        }
    }
    __builtin_amdgcn_s_setprio(0);
}

__global__ __launch_bounds__(512) void attn_kernel(const ushortT* __restrict__ qkv,
                                                   const ushortT* __restrict__ vgT,
                                                   ushortT* __restrict__ obf){
    __shared__ __align__(16) ushortT Ks[2][64*64];
    __shared__ __align__(16) ushortT Vs[2][64*64];
    __shared__ __align__(16) ushortT Plds[8][16][72];
    __shared__ __align__(16) float Alds[8][16];
    int bh = blockIdx.x, pairid = blockIdx.y;
    int b = bh >> 4, h = bh & 15;
    int tid = threadIdx.x, wid = tid >> 6, lane = tid & 63;
    int l15 = lane & 15, g = lane >> 4;
    int grp = wid >> 2, wg = wid & 3;

    const ushortT* Kg = qkv + (size_t)b * T_SEQ * TD + DM + h * DH;
    const ushortT* Vg = vgT + (size_t)bh * DH * T_SEQ;

    // staging: 512 threads x 16B = one full 64x64 bf16 tile per issue
    int st_row = wid*8 + (lane >> 3);
    int st_c   = (lane & 7) ^ ((lane >> 3) & 7);

#define STAGE_TILE(bufidx, kv0)                                                          \
    {                                                                                    \
        const ushortT* ksrc_ = Kg + (size_t)((kv0) + st_row) * TD + st_c*8;              \
        const ushortT* vsrc_ = Vg + (size_t)st_row * T_SEQ + (kv0) + st_c*8;             \
        gload_lds16(ksrc_, (char*)Ks[bufidx] + wid*1024);                                \
        gload_lds16(vsrc_, (char*)Vs[bufidx] + wid*1024);                                \
    }

    int pA = pairid, pB = 31 - pairid;
    int myp = grp ? pB : pA;

    QState S;
    {
        int qrow = myp*64 + wg*16 + l15;
        const ushortT* qb = qkv + ((size_t)b * T_SEQ + qrow) * TD + h * DH;
        S.qf0 = *(const bf16x8*)(qb + 8*g);
        S.qf1 = *(const bf16x8*)(qb + 32 + 8*g);
    }
#pragma unroll
    for (int j = 0; j < 8; j++){
        S.qf0[j] = (__bf16)((float)S.qf0[j] * 0.125f);
        S.qf1[j] = (__bf16)((float)S.qf1[j] * 0.125f);
    }
    S.m_ = -INFINITY; S.lsum = 0.f;
#pragma unroll
    for (int nt = 0; nt < 4; nt++) S.acc[nt] = (f32x4){0.f,0.f,0.f,0.f};

    STAGE_TILE(0, 0);
    __syncthreads();

    for (int t = 0; t <= pB; t++){
        int buf = t & 1;
        if (t < pB) STAGE_TILE(buf ^ 1, (t+1)*64);
        if (t <= myp)
            proc_tile(Ks[buf], Vs[buf], S, t == myp, wg, l15, g, Plds[wid], Alds[wid]);
        __syncthreads();
    }
#undef STAGE_TILE

    Alds[wid][l15] = 1.f / S.lsum;
    f32x4 i4 = *(const f32x4*)&Alds[wid][4*g];
#pragma unroll
    for (int jj = 0; jj < 4; jj++){
        int t = myp*64 + wg*16 + 4*g + jj;
#pragma unroll
        for (int nt = 0; nt < 4; nt++)
            obf[((size_t)b * T_SEQ + t) * DM + h*DH + nt*16 + l15] =
                f2bf(S.acc[nt][jj] * i4[jj]);
    }
}

extern "C" void kernel_launch(void* const* d_in, const int* in_sizes, int n_in,
                              void* d_out, int out_size, void* d_ws, size_t ws_size,
                              hipStream_t stream){
    const float* x    = (const float*)d_in[0];
    const float* Wqkv = (const float*)d_in[1];
    const float* bqkv = (const float*)d_in[2];
    const float* Wg   = (const float*)d_in[3];
    const float* Wout = (const float*)d_in[4];
    const float* bout = (const float*)d_in[5];

    char* ws = (char*)d_ws;
    ushortT* xbf   = (ushortT*)(ws);                 //  8 MB : (4096,1024) bf16
    ushortT* wqkvT = (ushortT*)(ws + 8388608);       //  6 MB : (3072,1024) bf16
    ushortT* woutT = (ushortT*)(ws + 14680064);      //  2 MB : (1024,1024) bf16
    ushortT* qkvb  = (ushortT*)(ws + 16777216);      // 24 MB : (4096,3072) bf16
    ushortT* vgT   = (ushortT*)(ws + 41943040);      //  8 MB : (32,64,2048) bf16
    ushortT* obf   = (ushortT*)(ws + 50331648);      //  8 MB : (4096,1024) bf16
    ushortT* wgT   = (ushortT*)(ws + 58720256);      // 128KB : (16,64,64) bf16

    cast_bf16_kernel<<<4096, 256, 0, stream>>>(x, xbf, 4194304);
    transcast_kernel<<<dim3(48,16), 256, 0, stream>>>(Wqkv, wqkvT, 1024, 3072);
    transcast_kernel<<<dim3(16,16), 256, 0, stream>>>(Wout, woutT, 1024, 1024);
    wg_transcast_kernel<<<16, 256, 0, stream>>>(Wg, wgT);
    gemm_bf16_kernel<ushortT><<<dim3(32,24), 256, 0, stream>>>(xbf, wqkvT, bqkv, qkvb, 4096, 3072, 1024);
    gate_kernel<<<dim3(32,32), 256, 0, stream>>>(qkvb, wgT, vgT);
    attn_kernel<<<dim3(32,16), 512, 0, stream>>>(qkvb, vgT, obf);
    gemm_bf16_kernel<float><<<dim3(32,8), 256, 0, stream>>>(obf, woutT, bout, (float*)d_out, 4096, 1024, 1024);
}

// Round 7
// 125.826 us; speedup vs baseline: 1.4932x; 1.0042x over previous
//
#include <hip/hip_runtime.h>
#include <hip/hip_bf16.h>

typedef unsigned short ushortT;
typedef __bf16 bf16x8 __attribute__((ext_vector_type(8)));
typedef __bf16 bf16x4 __attribute__((ext_vector_type(4)));
typedef float f32x4 __attribute__((ext_vector_type(4)));

#define T_SEQ 2048
#define DH 64
#define NH 16
#define DM 1024
#define TD 3072
#define BATCH 2
#define LOG2E 1.44269504f

__device__ inline ushortT f2bf(float f){
    union { float f; unsigned int u; } a; a.f = f;
    unsigned int r = a.u + 0x7fffu + ((a.u >> 16) & 1u);
    return (ushortT)(r >> 16);
}
__device__ inline float bf2f(ushortT u){
    union { float f; unsigned int u; } a; a.u = ((unsigned int)u) << 16;
    return a.f;
}

__device__ inline void gload_lds16(const void* g, void* l){
    __builtin_amdgcn_global_load_lds((const __attribute__((address_space(1))) void*)g,
                                     (__attribute__((address_space(3))) void*)l, 16, 0, 0);
}

// ---------------- cast x (fp32 -> bf16) ----------------
__global__ __launch_bounds__(256) void cast_bf16_kernel(const float* __restrict__ in,
                                                        ushortT* __restrict__ out, int n){
    int i = (blockIdx.x * 256 + threadIdx.x) * 4;
    if (i < n){
        float4 v = *(const float4*)&in[i];
        out[i+0] = f2bf(v.x); out[i+1] = f2bf(v.y);
        out[i+2] = f2bf(v.z); out[i+3] = f2bf(v.w);
    }
}

// ---------------- transpose + cast: in (K,N) fp32 -> out (N,K) bf16 ----------------
__global__ __launch_bounds__(256) void transcast_kernel(const float* __restrict__ in,
                                                        ushortT* __restrict__ out, int K, int N){
    __shared__ float tile[64][65];
    int n0 = blockIdx.x * 64, k0 = blockIdx.y * 64;
    int tid = threadIdx.x;
    int c  = tid & 63;
    int r4 = tid >> 6;
#pragma unroll
    for (int i = 0; i < 16; i++){
        int k = r4 + i * 4;
        tile[k][c] = in[(size_t)(k0 + k) * N + n0 + c];
    }
    __syncthreads();
#pragma unroll
    for (int i = 0; i < 16; i++){
        int n = r4 + i * 4;
        out[(size_t)(n0 + n) * K + k0 + c] = f2bf(tile[c][n]);
    }
}

// ---------------- Wg transpose: in [16][d=64][e=64] f32 -> out [16][e][d] bf16 ----------------
__global__ __launch_bounds__(256) void wg_transcast_kernel(const float* __restrict__ in,
                                                           ushortT* __restrict__ out){
    __shared__ float tile[64][65];
    int h = blockIdx.x;
    int tid = threadIdx.x;
    int c = tid & 63, r4 = tid >> 6;
#pragma unroll
    for (int i = 0; i < 16; i++){
        int d = r4 + i*4;
        tile[d][c] = in[h*4096 + d*64 + c];
    }
    __syncthreads();
#pragma unroll
    for (int i = 0; i < 16; i++){
        int e = r4 + i*4;
        out[h*4096 + e*64 + c] = f2bf(tile[c][e]);   // out[h][e][d=c]
    }
}

// ---------------- bf16 MFMA GEMM (2-phase double-buffered): C = A @ BT^T + bias ----------------
__device__ inline void store_out(ushortT* C, size_t i, float v){ C[i] = f2bf(v); }
__device__ inline void store_out(float*   C, size_t i, float v){ C[i] = v; }

template <typename OUT>
__global__ __launch_bounds__(256) void gemm_bf16_kernel(const ushortT* __restrict__ A,
                                                        const ushortT* __restrict__ BT,
                                                        const float* __restrict__ bias,
                                                        OUT* __restrict__ C,
                                                        int M, int N, int K){
    __shared__ __align__(16) ushortT As[2][128*32];
    __shared__ __align__(16) ushortT Bs[2][128*32];
    int tid = threadIdx.x;
    int m0 = blockIdx.x * 128;
    int n0 = blockIdx.y * 128;
    int wid = tid >> 6, lane = tid & 63;
    int l15 = lane & 15, g = lane >> 4;
    int wr = wid >> 1, wc = wid & 1;

    f32x4 acc[4][4];
#pragma unroll
    for (int i = 0; i < 4; i++)
#pragma unroll
        for (int j = 0; j < 4; j++) acc[i][j] = (f32x4){0.f,0.f,0.f,0.f};

    int srow = wid * 32 + (lane >> 2);
    int sch  = lane & 3;

#define GSTAGE(buf, k0)                                                                  \
    {                                                                                    \
        _Pragma("unroll")                                                                \
        for (int i_ = 0; i_ < 2; i_++){                                                  \
            int row_ = srow + i_ * 16;                                                   \
            const ushortT* asrc_ = A  + (size_t)(m0 + row_) * K + (k0) + sch * 8;        \
            const ushortT* bsrc_ = BT + (size_t)(n0 + row_) * K + (k0) + sch * 8;        \
            gload_lds16(asrc_, (char*)As[buf] + (wid*2 + i_) * 1024);                    \
            gload_lds16(bsrc_, (char*)Bs[buf] + (wid*2 + i_) * 1024);                    \
        }                                                                                \
    }

    GSTAGE(0, 0);
    __syncthreads();

    int nk = K >> 5;
    for (int kt = 0; kt < nk; kt++){
        int buf = kt & 1;
        if (kt + 1 < nk) GSTAGE(buf ^ 1, (kt + 1) * 32);

        bf16x8 af[4], bfr[4];
#pragma unroll
        for (int mi = 0; mi < 4; mi++){
            int r = wr*64 + mi*16 + l15;
            af[mi]  = *(const bf16x8*)(As[buf] + r*32 + g*8);
        }
#pragma unroll
        for (int ni = 0; ni < 4; ni++){
            int r = wc*64 + ni*16 + l15;
            bfr[ni] = *(const bf16x8*)(Bs[buf] + r*32 + g*8);
        }
#pragma unroll
        for (int mi = 0; mi < 4; mi++)
#pragma unroll
            for (int ni = 0; ni < 4; ni++)
                acc[mi][ni] = __builtin_amdgcn_mfma_f32_16x16x32_bf16(af[mi], bfr[ni], acc[mi][ni], 0, 0, 0);
        __syncthreads();
    }
#undef GSTAGE

#pragma unroll
    for (int mi = 0; mi < 4; mi++){
#pragma unroll
        for (int jj = 0; jj < 4; jj++){
            int mm = m0 + wr*64 + mi*16 + 4*g + jj;
#pragma unroll
            for (int ni = 0; ni < 4; ni++){
                int nn = n0 + wc*64 + ni*16 + l15;
                float v = acc[mi][ni][jj] + bias[nn];
                store_out(C, (size_t)mm * N + nn, v);
            }
        }
    }
}

// ---------------- gate (MFMA): g=sigmoid(Q @ Wg[h]); VgT[b,h,e,t] = g*v ----------------
__global__ __launch_bounds__(256) void gate_kernel(const ushortT* __restrict__ qkv,
                                                   const ushortT* __restrict__ WgT,
                                                   ushortT* __restrict__ vgT){
    __shared__ __align__(16) ushortT VT[64][72];
    int tblk = blockIdx.x, bh = blockIdx.y;
    int b = bh >> 4, h = bh & 15;
    int tid = threadIdx.x, wid = tid >> 6, lane = tid & 63;
    int l15 = lane & 15, g = lane >> 4;
    int t0 = tblk * 64;
    int tl = wid*16 + l15;

    const ushortT* qrow = qkv + ((size_t)b*T_SEQ + t0 + tl)*TD + h*DH;
    bf16x8 qf0 = *(const bf16x8*)(qrow + 8*g);
    bf16x8 qf1 = *(const bf16x8*)(qrow + 32 + 8*g);

    const ushortT* wbase = WgT + h*4096;
    const ushortT* vrow = qkv + ((size_t)b*T_SEQ + t0 + tl)*TD + 2*DM + h*DH;

#pragma unroll
    for (int ns = 0; ns < 4; ns++){
        int e = ns*16 + l15;
        bf16x8 wf0 = *(const bf16x8*)(wbase + e*64 + 8*g);
        bf16x8 wf1 = *(const bf16x8*)(wbase + e*64 + 32 + 8*g);
        f32x4 z = (f32x4){0.f,0.f,0.f,0.f};
        z = __builtin_amdgcn_mfma_f32_16x16x32_bf16(wf0, qf0, z, 0, 0, 0);
        z = __builtin_amdgcn_mfma_f32_16x16x32_bf16(wf1, qf1, z, 0, 0, 0);
        union { ushortT u[4]; uint2 v; } v4;
        v4.v = *(const uint2*)(vrow + ns*16 + 4*g);
#pragma unroll
        for (int jj = 0; jj < 4; jj++){
            float ex = __builtin_amdgcn_exp2f(-z[jj] * LOG2E);
            float gv = __builtin_amdgcn_rcpf(1.f + ex);
            VT[ns*16 + 4*g + jj][tl] = f2bf(gv * bf2f(v4.u[jj]));
        }
    }
    __syncthreads();
    for (int i = tid; i < 64*8; i += 256){
        int e = i >> 3, c8 = (i & 7) * 8;
        *(uint4*)&vgT[((size_t)bh * DH + e) * T_SEQ + t0 + c8] = *(const uint4*)&VT[e][c8];
    }
}

// ---------------- causal flash attention with gated V (fully register-resident softmax) ----
// grid: 512 1-D, remapped so CU-co-resident blocks get complementary causal work.
// 512-thread blocks: waves 0-3 -> qblk pA, waves 4-7 -> qblk pB.
// K tile staged with row bit-permutation pi(r) = [ns1|g1 g0|ns0|j1 j0] so the
// swapped-QK output (s[ns][jj], q on lane axis) IS the PV B-operand after packing.
// PV computes O^T (A=V^T) so q stays on lane axis: alpha/lsum/epilogue all lane-local.
struct QState {
    bf16x8 qf0, qf1;
    float m_, lsum;
    f32x4 acc[4];          // acc[nt][jj] = O^T[e=nt*16+4g+jj][q=l15]
};

__device__ __forceinline__ void proc_tile(const ushortT* __restrict__ Kb,
                                          const ushortT* __restrict__ Vb,
                                          QState& S, bool diag,
                                          int wg, int l15, int g){
    int l7 = l15 & 7;
    f32x4 s[4];
    __builtin_amdgcn_s_setprio(1);
#pragma unroll
    for (int ns = 0; ns < 4; ns++){
        int kr = ns*16 + l15;
        bf16x8 kf0 = *(const bf16x8*)(Kb + kr*64 + ((g    ) ^ l7)*8);
        bf16x8 kf1 = *(const bf16x8*)(Kb + kr*64 + ((4 + g) ^ l7)*8);
        f32x4 z = (f32x4){0.f,0.f,0.f,0.f};
        z = __builtin_amdgcn_mfma_f32_16x16x32_bf16(kf0, S.qf0, z, 0, 0, 0);
        z = __builtin_amdgcn_mfma_f32_16x16x32_bf16(kf1, S.qf1, z, 0, 0, 0);
        s[ns] = z;   // s[ns][jj] = score[kv = 32*(ns>>1) + 8g + 4*(ns&1) + jj][q=l15]
    }
    __builtin_amdgcn_s_setprio(0);

    float tmax = -INFINITY;
    if (diag){
        int qrel = wg*16 + l15;
#pragma unroll
        for (int ns = 0; ns < 4; ns++){
            int kbase = ((ns & 2) << 4) + 8*g + ((ns & 1) << 2);
#pragma unroll
            for (int jj = 0; jj < 4; jj++){
                if (kbase + jj > qrel) s[ns][jj] = -INFINITY;
                tmax = fmaxf(tmax, s[ns][jj]);
            }
        }
    } else {
#pragma unroll
        for (int ns = 0; ns < 4; ns++){
            float a = fmaxf(s[ns][0], s[ns][1]);
            float c = fmaxf(s[ns][2], s[ns][3]);
            tmax = fmaxf(tmax, fmaxf(a, c));
        }
    }
    tmax = fmaxf(tmax, __shfl_xor(tmax, 16, 64));
    tmax = fmaxf(tmax, __shfl_xor(tmax, 32, 64));

    float mnew = fmaxf(S.m_, tmax);
    float mc = mnew * LOG2E;
    float rs = 0.f;
    bf16x8 pa0, pa1;
#pragma unroll
    for (int jj = 0; jj < 4; jj++){
        float p0 = __builtin_amdgcn_exp2f(fmaf(s[0][jj], LOG2E, -mc));
        float p1 = __builtin_amdgcn_exp2f(fmaf(s[1][jj], LOG2E, -mc));
        float p2 = __builtin_amdgcn_exp2f(fmaf(s[2][jj], LOG2E, -mc));
        float p3 = __builtin_amdgcn_exp2f(fmaf(s[3][jj], LOG2E, -mc));
        rs += (p0 + p1) + (p2 + p3);
        pa0[jj]   = (__bf16)p0;
        pa0[4+jj] = (__bf16)p1;
        pa1[jj]   = (__bf16)p2;
        pa1[4+jj] = (__bf16)p3;
    }
    rs += __shfl_xor(rs, 16, 64);
    rs += __shfl_xor(rs, 32, 64);

    if (!__all(mnew == S.m_)){
        float alpha = __builtin_amdgcn_exp2f(fmaf(S.m_, LOG2E, -mc));
#pragma unroll
        for (int nt = 0; nt < 4; nt++)
#pragma unroll
            for (int jj = 0; jj < 4; jj++) S.acc[nt][jj] *= alpha;
        S.lsum *= alpha;
        S.m_ = mnew;
    }
    S.lsum += rs;

    __builtin_amdgcn_s_setprio(1);
#pragma unroll
    for (int ks = 0; ks < 2; ks++){
        bf16x8 pa = ks ? pa1 : pa0;
#pragma unroll
        for (int nt = 0; nt < 4; nt++){
            bf16x8 vf = *(const bf16x8*)(Vb + (nt*16 + l15)*64 + ((ks*4 + g) ^ l7)*8);
            S.acc[nt] = __builtin_amdgcn_mfma_f32_16x16x32_bf16(vf, pa, S.acc[nt], 0, 0, 0);
        }
    }
    __builtin_amdgcn_s_setprio(0);
}

__global__ __launch_bounds__(512) void attn_kernel(const ushortT* __restrict__ qkv,
                                                   const ushortT* __restrict__ vgT,
                                                   ushortT* __restrict__ obf){
    __shared__ __align__(16) ushortT Ks[2][64*64];
    __shared__ __align__(16) ushortT Vs[2][64*64];
    // CU-balanced remap: ids c and c+256 (same CU under round-robin) get pair p and 15-p
    int id = blockIdx.x;
    int half = id >> 8, j = id & 255;
    int bh = (half << 4) | (j >> 4);
    int pp = j & 15;
    int pairid = half ? (15 - pp) : pp;
    int b = bh >> 4, h = bh & 15;
    int tid = threadIdx.x, wid = tid >> 6, lane = tid & 63;
    int l15 = lane & 15, g = lane >> 4;
    int grp = wid >> 2, wg = wid & 3;

    const ushortT* Kg = qkv + (size_t)b * T_SEQ * TD + DM + h * DH;
    const ushortT* Vg = vgT + (size_t)bh * DH * T_SEQ;

    // staging: 512 threads x 16B = one full 64x64 bf16 tile per issue
    int st_row = wid*8 + (lane >> 3);
    int st_c   = (lane & 7) ^ ((lane >> 3) & 7);
    // K rows staged permuted: LDS row r holds global key pi(r)
    int st_prow = (st_row & 0x20) | ((st_row & 0x0C) << 1) | ((st_row & 0x10) >> 2) | (st_row & 3);

#define STAGE_TILE(bufidx, kv0)                                                          \
    {                                                                                    \
        const ushortT* ksrc_ = Kg + (size_t)((kv0) + st_prow) * TD + st_c*8;             \
        const ushortT* vsrc_ = Vg + (size_t)st_row * T_SEQ + (kv0) + st_c*8;             \
        gload_lds16(ksrc_, (char*)Ks[bufidx] + wid*1024);                                \
        gload_lds16(vsrc_, (char*)Vs[bufidx] + wid*1024);                                \
    }

    int pA = pairid, pB = 31 - pairid;
    int myp = grp ? pB : pA;

    QState S;
    {
        int qrow = myp*64 + wg*16 + l15;
        const ushortT* qb = qkv + ((size_t)b * T_SEQ + qrow) * TD + h * DH;
        S.qf0 = *(const bf16x8*)(qb + 8*g);
        S.qf1 = *(const bf16x8*)(qb + 32 + 8*g);
    }
#pragma unroll
    for (int jq = 0; jq < 8; jq++){
        S.qf0[jq] = (__bf16)((float)S.qf0[jq] * 0.125f);
        S.qf1[jq] = (__bf16)((float)S.qf1[jq] * 0.125f);
    }
    S.m_ = -INFINITY; S.lsum = 0.f;
#pragma unroll
    for (int nt = 0; nt < 4; nt++) S.acc[nt] = (f32x4){0.f,0.f,0.f,0.f};

    STAGE_TILE(0, 0);
    __syncthreads();

    for (int t = 0; t <= pB; t++){
        int buf = t & 1;
        if (t < pB) STAGE_TILE(buf ^ 1, (t+1)*64);
        if (t <= myp)
            proc_tile(Ks[buf], Vs[buf], S, t == myp, wg, l15, g);
        __syncthreads();
    }
#undef STAGE_TILE

    float inv = 1.f / S.lsum;
    size_t orow = ((size_t)b * T_SEQ + myp*64 + wg*16 + l15) * DM + h*DH;
#pragma unroll
    for (int nt = 0; nt < 4; nt++){
        union { ushortT u[4]; uint2 v; } pk;
#pragma unroll
        for (int jj = 0; jj < 4; jj++) pk.u[jj] = f2bf(S.acc[nt][jj] * inv);
        *(uint2*)&obf[orow + nt*16 + 4*g] = pk.v;
    }
}

extern "C" void kernel_launch(void* const* d_in, const int* in_sizes, int n_in,
                              void* d_out, int out_size, void* d_ws, size_t ws_size,
                              hipStream_t stream){
    const float* x    = (const float*)d_in[0];
    const float* Wqkv = (const float*)d_in[1];
    const float* bqkv = (const float*)d_in[2];
    const float* Wg   = (const float*)d_in[3];
    const float* Wout = (const float*)d_in[4];
    const float* bout = (const float*)d_in[5];

    char* ws = (char*)d_ws;
    ushortT* xbf   = (ushortT*)(ws);                 //  8 MB : (4096,1024) bf16
    ushortT* wqkvT = (ushortT*)(ws + 8388608);       //  6 MB : (3072,1024) bf16
    ushortT* woutT = (ushortT*)(ws + 14680064);      //  2 MB : (1024,1024) bf16
    ushortT* qkvb  = (ushortT*)(ws + 16777216);      // 24 MB : (4096,3072) bf16
    ushortT* vgT   = (ushortT*)(ws + 41943040);      //  8 MB : (32,64,2048) bf16
    ushortT* obf   = (ushortT*)(ws + 50331648);      //  8 MB : (4096,1024) bf16
    ushortT* wgT   = (ushortT*)(ws + 58720256);      // 128KB : (16,64,64) bf16

    cast_bf16_kernel<<<4096, 256, 0, stream>>>(x, xbf, 4194304);
    transcast_kernel<<<dim3(48,16), 256, 0, stream>>>(Wqkv, wqkvT, 1024, 3072);
    transcast_kernel<<<dim3(16,16), 256, 0, stream>>>(Wout, woutT, 1024, 1024);
    wg_transcast_kernel<<<16, 256, 0, stream>>>(Wg, wgT);
    gemm_bf16_kernel<ushortT><<<dim3(32,24), 256, 0, stream>>>(xbf, wqkvT, bqkv, qkvb, 4096, 3072, 1024);
    gate_kernel<<<dim3(32,32), 256, 0, stream>>>(qkvb, wgT, vgT);
    attn_kernel<<<512, 512, 0, stream>>>(qkvb, vgT, obf);
    gemm_bf16_kernel<float><<<dim3(32,8), 256, 0, stream>>>(obf, woutT, bout, (float*)d_out, 4096, 1024, 1024);
}